// Round 2
// baseline (28650.299 us; speedup 1.0000x reference)
//
#include <hip/hip_runtime.h>
#include <hip/hip_bf16.h>

// Problem dims (fixed)
#define B 64
#define T 512
#define D 1024
#define KC 256
#define NQ (B*T*D)      // 33554432
#define NI (B*T)        // 32768
#define RING 64         // hproj ring steps

// ---- numpy-faithful fp32 pairwise sum of squares, n=1024 (8 leaves of 128) ----
__device__ inline float np_pairwise_sq_1024(const float* a, int stride) {
    float L[8];
    for (int c = 0; c < 8; ++c) {
        const float* p = a + c * 128 * stride;
        float r[8];
        #pragma unroll
        for (int k = 0; k < 8; ++k) r[k] = __fmul_rn(p[k*stride], p[k*stride]);
        for (int i = 8; i < 128; i += 8) {
            #pragma unroll
            for (int k = 0; k < 8; ++k) {
                float v = p[(i + k) * stride];
                r[k] = __fadd_rn(r[k], __fmul_rn(v, v));
            }
        }
        L[c] = __fadd_rn(__fadd_rn(__fadd_rn(r[0], r[1]), __fadd_rn(r[2], r[3])),
                         __fadd_rn(__fadd_rn(r[4], r[5]), __fadd_rn(r[6], r[7])));
    }
    return __fadd_rn(__fadd_rn(__fadd_rn(L[0], L[1]), __fadd_rn(L[2], L[3])),
                     __fadd_rn(__fadd_rn(L[4], L[5]), __fadd_rn(L[6], L[7])));
}

// ---------------- codebook norms (fp32, numpy pairwise) ----------------
__global__ __launch_bounds__(256) void c2_kernel(const float* __restrict__ cb,
                                                 float* __restrict__ c2) {
    int j = threadIdx.x;   // 1 block, 256 threads
    c2[j] = np_pairwise_sq_1024(cb + (size_t)j * D, 1);
}

// ---------------- quantize: fp32-faithful argmin, 8 rows/block ----------------
__global__ __launch_bounds__(256) void quantize_kernel(const float* __restrict__ Z,
                                                       const float* __restrict__ cb,
                                                       const float* __restrict__ c2,
                                                       float* __restrict__ qout,
                                                       float* __restrict__ idxout) {
    __shared__ float rows[8][D];      // 32 KB
    __shared__ float z2s[8];
    __shared__ float d2s[256];
    __shared__ int   idxs[256];
    __shared__ int   bestIdx[8];
    int tid = threadIdx.x;
    size_t row0 = (size_t)blockIdx.x * 8;

    for (int p = 0; p < 8; ++p) {
        float4 v = *reinterpret_cast<const float4*>(Z + (row0 + p) * D + tid * 4);
        *reinterpret_cast<float4*>(&rows[p][tid * 4]) = v;
    }
    __syncthreads();

    if (tid < 8) z2s[tid] = np_pairwise_sq_1024(rows[tid], 1);

    // g2[r] = sequential-FMA sum over e of (2*z_e)*c_e  (matches sgemm k-order)
    float g2[8];
    #pragma unroll
    for (int r = 0; r < 8; ++r) g2[r] = 0.0f;
    const float* crow = cb + (size_t)tid * D;
    for (int e = 0; e < D; ++e) {
        float ce = crow[e];
        #pragma unroll
        for (int r = 0; r < 8; ++r)
            g2[r] = __fmaf_rn(__fmul_rn(2.0f, rows[r][e]), ce, g2[r]);
    }
    __syncthreads();   // z2s ready

    for (int r = 0; r < 8; ++r) {
        d2s[tid] = __fadd_rn(__fsub_rn(z2s[r], g2[r]), c2[tid]);
        idxs[tid] = tid;
        __syncthreads();
        for (int s = 128; s > 0; s >>= 1) {
            if (tid < s) {
                float ov = d2s[tid + s]; int oi = idxs[tid + s];
                if (ov < d2s[tid] || (ov == d2s[tid] && oi < idxs[tid])) {
                    d2s[tid] = ov; idxs[tid] = oi;
                }
            }
            __syncthreads();
        }
        if (tid == 0) bestIdx[r] = idxs[0];
        __syncthreads();
    }

    if (tid < 8) idxout[row0 + tid] = (float)bestIdx[tid];
    for (int r = 0; r < 8; ++r) {
        int bi = bestIdx[r];
        float4 v = *reinterpret_cast<const float4*>(cb + (size_t)bi * D + tid * 4);
        *reinterpret_cast<float4*>(qout + (row0 + r) * D + tid * 4) = v;
    }
}

// ---------------- per-step GEMMs: gi, gh, proj(t-1) into ring ----------------
__global__ __launch_bounds__(256) void step_kernel(const float* __restrict__ quantized,
                                                   const float* __restrict__ h,
                                                   const float* __restrict__ Wih,
                                                   const float* __restrict__ Whh,
                                                   const float* __restrict__ projW,
                                                   const float* __restrict__ projb,
                                                   float* __restrict__ gh6,
                                                   float* __restrict__ ring,
                                                   int t) {
    int bid = blockIdx.x;           // 224 blocks
    const float* A; size_t lda; const float* W;
    float* out; size_t ldo; int n0; int useBias = 0;

    if (bid < 96) {                 // gi = x_t @ Wih^T
        if (t >= T) return;
        n0 = bid * 32;
        A = quantized + (size_t)t * D; lda = (size_t)T * D;
        W = Wih + (size_t)n0 * D;
        out = gh6 + n0; ldo = 6144;
    } else if (bid < 192) {         // gh = h @ Whh^T
        if (t >= T) return;
        n0 = (bid - 96) * 32;
        A = h; lda = D;
        W = Whh + (size_t)n0 * D;
        out = gh6 + 3072 + n0; ldo = 6144;
    } else {                        // proj of h_{t-1} into ring slot (t-1)%64
        if (t == 0) return;
        n0 = (bid - 192) * 32;
        A = h; lda = D;
        W = projW + (size_t)n0 * D;
        out = ring + (size_t)((t - 1) & (RING - 1)) * (B * D) + n0; ldo = D;
        useBias = 1;
    }

    __shared__ float As[64][33];
    __shared__ float Ws[32][33];
    int tid = threadIdx.x;
    int tx = tid & 15, ty = tid >> 4;
    float acc[4][2] = {{0.f,0.f},{0.f,0.f},{0.f,0.f},{0.f,0.f}};
    int r = tid >> 3;               // 0..31
    int c = (tid & 7) << 2;         // 0..28

    for (int kc = 0; kc < D; kc += 32) {
        float4 a0 = *reinterpret_cast<const float4*>(A + (size_t)r        * lda + kc + c);
        float4 a1 = *reinterpret_cast<const float4*>(A + (size_t)(r + 32) * lda + kc + c);
        float4 w0 = *reinterpret_cast<const float4*>(W + (size_t)r        * D   + kc + c);
        As[r][c] = a0.x; As[r][c+1] = a0.y; As[r][c+2] = a0.z; As[r][c+3] = a0.w;
        As[r+32][c] = a1.x; As[r+32][c+1] = a1.y; As[r+32][c+2] = a1.z; As[r+32][c+3] = a1.w;
        Ws[r][c] = w0.x; Ws[r][c+1] = w0.y; Ws[r][c+2] = w0.z; Ws[r][c+3] = w0.w;
        __syncthreads();
        #pragma unroll
        for (int kk = 0; kk < 32; ++kk) {
            float b0 = Ws[2*tx][kk], b1 = Ws[2*tx+1][kk];
            #pragma unroll
            for (int i = 0; i < 4; ++i) {
                float a = As[ty + 16*i][kk];
                acc[i][0] = __fmaf_rn(a, b0, acc[i][0]);
                acc[i][1] = __fmaf_rn(a, b1, acc[i][1]);
            }
        }
        __syncthreads();
    }

    #pragma unroll
    for (int i = 0; i < 4; ++i) {
        int m = ty + 16*i;
        #pragma unroll
        for (int cc = 0; cc < 2; ++cc) {
            int n = 2*tx + cc;
            float v = acc[i][cc];
            if (useBias) v = __fadd_rn(v, projb[n0 + n]);
            out[(size_t)m * ldo + n] = v;
        }
    }
}

// ---------------- GRU gates, h updated in place ----------------
__global__ __launch_bounds__(256) void gates_kernel(const float* __restrict__ gh6,
                                                    const float* __restrict__ bih,
                                                    const float* __restrict__ bhh,
                                                    float* __restrict__ h) {
    int e = blockIdx.x * 256 + threadIdx.x;   // B*D = 65536
    int b = e >> 10, j = e & 1023;
    const float* g = gh6 + (size_t)b * 6144;
    float gir = g[j],        giz = g[1024 + j], gin = g[2048 + j];
    float ghr = g[3072 + j], ghz = g[4096 + j], ghn = g[5120 + j];
    float rr = 1.0f / (1.0f + expf(-(gir + bih[j]        + ghr + bhh[j])));
    float zz = 1.0f / (1.0f + expf(-(giz + bih[1024 + j] + ghz + bhh[1024 + j])));
    float nn = tanhf(gin + bih[2048 + j] + rr * (ghn + bhh[2048 + j]));
    float hv = h[e];
    h[e] = (1.0f - zz) * nn + zz * hv;
}

// ---------------- CPC loss for one 64-step chunk ----------------
__global__ __launch_bounds__(256) void cpc_loss_kernel(const float* __restrict__ ring,
                                                       const float* __restrict__ Z,
                                                       double* __restrict__ cp_sum,
                                                       int chunk) {
    int slot = blockIdx.x;               // 0..63
    int tp = chunk * 64 + slot;          // t'
    int k = blockIdx.y + 1;              // 1..3
    if (tp >= T - k) return;
    __shared__ float Hs[64][33];
    __shared__ float Zs[64][33];
    int tid = threadIdx.x;
    int tx = tid & 15, ty = tid >> 4;
    float acc[4][4] = {};
    const float* Hbase = ring + (size_t)slot * (B * D);
    const float* Zbase = Z + (size_t)(tp + k) * D;
    const size_t zstride = (size_t)T * D;
    int r = tid >> 3, c = (tid & 7) << 2;

    for (int kc = 0; kc < D; kc += 32) {
        #pragma unroll
        for (int p = 0; p < 2; ++p) {
            int rr2 = r + 32 * p;
            float4 hv = *reinterpret_cast<const float4*>(Hbase + (size_t)rr2 * D + kc + c);
            float4 zv = *reinterpret_cast<const float4*>(Zbase + (size_t)rr2 * zstride + kc + c);
            Hs[rr2][c] = hv.x; Hs[rr2][c+1] = hv.y; Hs[rr2][c+2] = hv.z; Hs[rr2][c+3] = hv.w;
            Zs[rr2][c] = zv.x; Zs[rr2][c+1] = zv.y; Zs[rr2][c+2] = zv.z; Zs[rr2][c+3] = zv.w;
        }
        __syncthreads();
        #pragma unroll
        for (int kk = 0; kk < 32; ++kk) {
            float av[4], bv[4];
            #pragma unroll
            for (int i = 0; i < 4; ++i) av[i] = Hs[ty + 16*i][kk];
            #pragma unroll
            for (int j = 0; j < 4; ++j) bv[j] = Zs[tx + 16*j][kk];
            #pragma unroll
            for (int i = 0; i < 4; ++i)
                #pragma unroll
                for (int j = 0; j < 4; ++j)
                    acc[i][j] = __fmaf_rn(av[i], bv[j], acc[i][j]);
        }
        __syncthreads();
    }

    double lsum = 0.0;
    #pragma unroll
    for (int i = 0; i < 4; ++i) {
        #pragma unroll
        for (int j = 0; j < 4; ++j) {
            int bb = ty + 16*i, cc2 = tx + 16*j;
            double v = (double)acc[i][j];
            double s = 1.0 / (1.0 + exp(-v));
            lsum += (0.1 / 4096.0) * (-log(1.0 - s + 1e-8));
            if (bb == cc2) lsum += (1.0 / 64.0) * (-log(s + 1e-8));
        }
    }
    __shared__ double red[256];
    red[tid] = lsum; __syncthreads();
    for (int s2 = 128; s2 > 0; s2 >>= 1) {
        if (tid < s2) red[tid] += red[tid + s2];
        __syncthreads();
    }
    if (tid == 0) atomicAdd(cp_sum, red[0]);
}

// ---------------- VQ loss ----------------
__global__ __launch_bounds__(256) void vq_kernel(const float* __restrict__ Z,
                                                 const float* __restrict__ Q,
                                                 double* __restrict__ vq_sum) {
    size_t i0 = ((size_t)blockIdx.x * 256 + threadIdx.x) * 4;
    const size_t stride = (size_t)2048 * 256 * 4;
    double s = 0.0;
    for (size_t i = i0; i < (size_t)NQ; i += stride) {
        float4 z = *reinterpret_cast<const float4*>(Z + i);
        float4 q = *reinterpret_cast<const float4*>(Q + i);
        double d0 = (double)z.x - (double)q.x;
        double d1 = (double)z.y - (double)q.y;
        double d2 = (double)z.z - (double)q.z;
        double d3 = (double)z.w - (double)q.w;
        s += d0*d0 + d1*d1 + d2*d2 + d3*d3;
    }
    __shared__ double red[256];
    int tid = threadIdx.x;
    red[tid] = s; __syncthreads();
    for (int k = 128; k > 0; k >>= 1) {
        if (tid < k) red[tid] += red[tid + k];
        __syncthreads();
    }
    if (tid == 0) atomicAdd(vq_sum, red[0]);
}

// ---------------- finalize scalars ----------------
__global__ void finalize_kernel(const double* __restrict__ accum,
                                float* __restrict__ scal) {
    double cp = accum[0] / 1527.0;
    double vq = accum[1] * 1.25 / (double)NQ;
    scal[0] = (float)(cp + vq);
    scal[1] = (float)cp;
    scal[2] = (float)vq;
}

extern "C" void kernel_launch(void* const* d_in, const int* in_sizes, int n_in,
                              void* d_out, int out_size, void* d_ws, size_t ws_size,
                              hipStream_t stream) {
    const float* Z     = (const float*)d_in[0];
    const float* cb    = (const float*)d_in[1];
    const float* Wih   = (const float*)d_in[2];
    const float* Whh   = (const float*)d_in[3];
    const float* bih   = (const float*)d_in[4];
    const float* bhh   = (const float*)d_in[5];
    const float* projW = (const float*)d_in[6];
    const float* projb = (const float*)d_in[7];

    float* out       = (float*)d_out;
    float* quantized = out;
    float* idxout    = out + (size_t)NQ;
    float* scal      = out + (size_t)NQ + NI;

    // ws layout (total ~18.6 MB)
    char* ws = (char*)d_ws;
    float*  ring  = (float*)ws;                      // 64*B*D*4 = 16,777,216 B
    float*  gh6   = (float*)(ws + 16777216);         // B*6144*4 = 1,572,864 B
    float*  h     = (float*)(ws + 18350080);         // B*D*4    =   262,144 B
    float*  c2f   = (float*)(ws + 18612224);         // 1 KB
    double* accum = (double*)(ws + 18613248);        // 16 B (8-aligned)

    hipMemsetAsync(h, 0, 262144, stream);
    hipMemsetAsync(accum, 0, 16, stream);

    c2_kernel<<<1, 256, 0, stream>>>(cb, c2f);
    quantize_kernel<<<4096, 256, 0, stream>>>(Z, cb, c2f, quantized, idxout);

    for (int t = 0; t <= T; ++t) {
        step_kernel<<<224, 256, 0, stream>>>(quantized, h, Wih, Whh, projW, projb,
                                             gh6, ring, t);
        if (t > 0 && (t & 63) == 0)
            cpc_loss_kernel<<<dim3(64, 3), 256, 0, stream>>>(ring, Z, &accum[0], t / 64 - 1);
        if (t < T) gates_kernel<<<256, 256, 0, stream>>>(gh6, bih, bhh, h);
    }

    vq_kernel<<<2048, 256, 0, stream>>>(Z, quantized, &accum[1]);
    finalize_kernel<<<1, 1, 0, stream>>>(accum, scal);
}

// Round 3
// 12952.184 us; speedup vs baseline: 2.2120x; 2.2120x over previous
//
#include <hip/hip_runtime.h>
#include <hip/hip_bf16.h>

// Problem dims (fixed)
#define B_ 64
#define T_ 512
#define D_ 1024
#define NCODE 256
#define NQ_ (B_*T_*D_)      // 33554432
#define NI_ (B_*T_)         // 32768

typedef __attribute__((ext_vector_type(8))) short bf16x8;
typedef __attribute__((ext_vector_type(4))) float f32x4;

__device__ inline ushort f2bf(float f) {
    uint x = __float_as_uint(f);
    return (ushort)((x + 0x7FFFu + ((x >> 16) & 1u)) >> 16);
}
__device__ inline float bf2f(ushort u) { return __uint_as_float(((uint)u) << 16); }

// ---------------- fp32 -> bf16 weight conversion ----------------
__global__ __launch_bounds__(256) void conv_kernel(const float* __restrict__ src,
                                                   ushort* __restrict__ dst, int n) {
    int i = (blockIdx.x * 256 + threadIdx.x) * 4;
    if (i >= n) return;
    float4 v = *reinterpret_cast<const float4*>(src + i);
    ushort4 o;
    o.x = f2bf(v.x); o.y = f2bf(v.y); o.z = f2bf(v.z); o.w = f2bf(v.w);
    *reinterpret_cast<ushort4*>(dst + i) = o;
}

// ---- numpy-faithful fp32 pairwise sum of squares, n=1024 (8 leaves of 128) ----
__device__ inline float np_pairwise_sq_1024(const float* a) {
    float L[8];
    for (int c = 0; c < 8; ++c) {
        const float* p = a + c * 128;
        float r[8];
        #pragma unroll
        for (int k = 0; k < 8; ++k) r[k] = __fmul_rn(p[k], p[k]);
        for (int i = 8; i < 128; i += 8) {
            #pragma unroll
            for (int k = 0; k < 8; ++k) {
                float v = p[i + k];
                r[k] = __fadd_rn(r[k], __fmul_rn(v, v));
            }
        }
        L[c] = __fadd_rn(__fadd_rn(__fadd_rn(r[0], r[1]), __fadd_rn(r[2], r[3])),
                         __fadd_rn(__fadd_rn(r[4], r[5]), __fadd_rn(r[6], r[7])));
    }
    return __fadd_rn(__fadd_rn(__fadd_rn(L[0], L[1]), __fadd_rn(L[2], L[3])),
                     __fadd_rn(__fadd_rn(L[4], L[5]), __fadd_rn(L[6], L[7])));
}

// ---------------- codebook norms (fp32, numpy pairwise) ----------------
__global__ __launch_bounds__(256) void c2_kernel(const float* __restrict__ cb,
                                                 float* __restrict__ c2) {
    int j = threadIdx.x;
    c2[j] = np_pairwise_sq_1024(cb + (size_t)j * D_);
}

// ---------------- quantize: fp32-faithful argmin, 8 rows/block ----------------
__global__ __launch_bounds__(256) void quantize_kernel(const float* __restrict__ Z,
                                                       const float* __restrict__ cb,
                                                       const float* __restrict__ c2,
                                                       float* __restrict__ qout,
                                                       float* __restrict__ idxout) {
    __shared__ float rows[8][D_];      // 32 KB
    __shared__ float z2s[8];
    __shared__ float d2s[256];
    __shared__ int   idxs[256];
    __shared__ int   bestIdx[8];
    int tid = threadIdx.x;
    size_t row0 = (size_t)blockIdx.x * 8;

    for (int p = 0; p < 8; ++p) {
        float4 v = *reinterpret_cast<const float4*>(Z + (row0 + p) * D_ + tid * 4);
        *reinterpret_cast<float4*>(&rows[p][tid * 4]) = v;
    }
    __syncthreads();

    if (tid < 8) z2s[tid] = np_pairwise_sq_1024(rows[tid]);

    float g2[8];
    #pragma unroll
    for (int r = 0; r < 8; ++r) g2[r] = 0.0f;
    const float* crow = cb + (size_t)tid * D_;
    for (int e = 0; e < D_; e += 4) {
        float4 cv = *reinterpret_cast<const float4*>(crow + e);
        #pragma unroll
        for (int r = 0; r < 8; ++r) {
            g2[r] = __fmaf_rn(__fmul_rn(2.0f, rows[r][e]),     cv.x, g2[r]);
            g2[r] = __fmaf_rn(__fmul_rn(2.0f, rows[r][e + 1]), cv.y, g2[r]);
            g2[r] = __fmaf_rn(__fmul_rn(2.0f, rows[r][e + 2]), cv.z, g2[r]);
            g2[r] = __fmaf_rn(__fmul_rn(2.0f, rows[r][e + 3]), cv.w, g2[r]);
        }
    }
    __syncthreads();

    for (int r = 0; r < 8; ++r) {
        d2s[tid] = __fadd_rn(__fsub_rn(z2s[r], g2[r]), c2[tid]);
        idxs[tid] = tid;
        __syncthreads();
        for (int s = 128; s > 0; s >>= 1) {
            if (tid < s) {
                float ov = d2s[tid + s]; int oi = idxs[tid + s];
                if (ov < d2s[tid] || (ov == d2s[tid] && oi < idxs[tid])) {
                    d2s[tid] = ov; idxs[tid] = oi;
                }
            }
            __syncthreads();
        }
        if (tid == 0) bestIdx[r] = idxs[0];
        __syncthreads();
    }

    if (tid < 8) idxout[row0 + tid] = (float)bestIdx[tid];
    for (int r = 0; r < 8; ++r) {
        int bi = bestIdx[r];
        float4 v = *reinterpret_cast<const float4*>(cb + (size_t)bi * D_ + tid * 4);
        *reinterpret_cast<float4*>(qout + (row0 + r) * D_ + tid * 4) = v;
    }
}

// ---------------- gi chunk GEMM: gi[s][b][n] = x_t[b] . Wih[n], bf16 MFMA ----------------
// grid (CH, 48); block 256 = 4 waves; m-tile = one s (64 b-rows), n-tile 64
__global__ __launch_bounds__(256) void gi_gemm_kernel(const float* __restrict__ quantized,
                                                      const ushort* __restrict__ Wih_bf,
                                                      ushort* __restrict__ gi,
                                                      int t0) {
    int s = blockIdx.x;
    int n0 = blockIdx.y * 64;
    __shared__ ushort As[64][136];   // 64 rows x 128 k, pad to 136
    __shared__ ushort Bs[64][136];
    int tid = threadIdx.x;
    int w = tid >> 6, l = tid & 63, lr = l & 15, lk = l >> 4;
    f32x4 acc[4] = {};

    for (int kc = 0; kc < D_; kc += 128) {
        for (int u = tid; u < 1024; u += 256) {      // A: fp32 -> bf16
            int r = u >> 4; int kp = (u & 15) * 8;
            const float* src = quantized + ((size_t)r * T_ + (t0 + s)) * D_ + kc + kp;
            float4 f0 = *reinterpret_cast<const float4*>(src);
            float4 f1 = *reinterpret_cast<const float4*>(src + 4);
            uint4 pk;
            pk.x = (uint)f2bf(f0.x) | ((uint)f2bf(f0.y) << 16);
            pk.y = (uint)f2bf(f0.z) | ((uint)f2bf(f0.w) << 16);
            pk.z = (uint)f2bf(f1.x) | ((uint)f2bf(f1.y) << 16);
            pk.w = (uint)f2bf(f1.z) | ((uint)f2bf(f1.w) << 16);
            *reinterpret_cast<uint4*>(&As[r][kp]) = pk;
        }
        for (int u = tid; u < 1024; u += 256) {      // B: bf16 direct
            int r = u >> 4; int kp = (u & 15) * 8;
            *reinterpret_cast<uint4*>(&Bs[r][kp]) =
                *reinterpret_cast<const uint4*>(Wih_bf + (size_t)(n0 + r) * D_ + kc + kp);
        }
        __syncthreads();
        #pragma unroll
        for (int kk = 0; kk < 4; ++kk) {
            bf16x8 b = *reinterpret_cast<const bf16x8*>(&Bs[16 * w + lr][kk * 32 + lk * 8]);
            #pragma unroll
            for (int mi = 0; mi < 4; ++mi) {
                bf16x8 a = *reinterpret_cast<const bf16x8*>(&As[16 * mi + lr][kk * 32 + lk * 8]);
                acc[mi] = __builtin_amdgcn_mfma_f32_16x16x32_bf16(a, b, acc[mi], 0, 0, 0);
            }
        }
        __syncthreads();
    }
    int n = n0 + 16 * w + lr;
    #pragma unroll
    for (int mi = 0; mi < 4; ++mi) {
        #pragma unroll
        for (int reg = 0; reg < 4; ++reg) {
            int b = 16 * mi + 4 * lk + reg;
            gi[((size_t)s * 64 + b) * 3072 + n] = f2bf(acc[mi][reg]);
        }
    }
}

// ---------------- fused per-step: gh MFMA + gates + h update ----------------
// grid 64 blocks (16-j tiles); block 256 = 4 waves (16 b-rows each)
__global__ __launch_bounds__(256) void fused_step_kernel(const ushort* __restrict__ Whh_bf,
                                                         const ushort* __restrict__ gi,
                                                         const float* __restrict__ bih,
                                                         const float* __restrict__ bhh,
                                                         float* __restrict__ h,
                                                         const ushort* __restrict__ h_bf_in,
                                                         ushort* __restrict__ h_bf_out,
                                                         ushort* __restrict__ h_hist,
                                                         int s) {
    int j0 = blockIdx.x * 16;
    __shared__ ushort Hs[64][136];
    __shared__ ushort Ws[48][136];
    int tid = threadIdx.x;
    int w = tid >> 6, l = tid & 63, lr = l & 15, lk = l >> 4;
    f32x4 acc[3] = {};

    for (int kc = 0; kc < D_; kc += 128) {
        for (int u = tid; u < 1024; u += 256) {      // stage h (all 64 b rows)
            int r = u >> 4; int kp = (u & 15) * 8;
            *reinterpret_cast<uint4*>(&Hs[r][kp]) =
                *reinterpret_cast<const uint4*>(h_bf_in + (size_t)r * D_ + kc + kp);
        }
        for (int u = tid; u < 768; u += 256) {       // stage Whh rows for 3 gates x 16 j
            int r = u >> 4; int kp = (u & 15) * 8;
            int g = r >> 4, nl = r & 15;
            *reinterpret_cast<uint4*>(&Ws[r][kp]) =
                *reinterpret_cast<const uint4*>(Whh_bf + (size_t)(g * 1024 + j0 + nl) * D_ + kc + kp);
        }
        __syncthreads();
        #pragma unroll
        for (int kk = 0; kk < 4; ++kk) {
            bf16x8 a = *reinterpret_cast<const bf16x8*>(&Hs[16 * w + lr][kk * 32 + lk * 8]);
            #pragma unroll
            for (int g = 0; g < 3; ++g) {
                bf16x8 bb = *reinterpret_cast<const bf16x8*>(&Ws[16 * g + lr][kk * 32 + lk * 8]);
                acc[g] = __builtin_amdgcn_mfma_f32_16x16x32_bf16(a, bb, acc[g], 0, 0, 0);
            }
        }
        __syncthreads();
    }

    int j = j0 + lr;
    float bihr = bih[j], bihz = bih[1024 + j], bihn = bih[2048 + j];
    float bhhr = bhh[j], bhhz = bhh[1024 + j], bhhn = bhh[2048 + j];
    const ushort* gis = gi + (size_t)s * 64 * 3072;
    #pragma unroll
    for (int reg = 0; reg < 4; ++reg) {
        int b = 16 * w + 4 * lk + reg;
        float gir = bf2f(gis[(size_t)b * 3072 + j]);
        float giz = bf2f(gis[(size_t)b * 3072 + 1024 + j]);
        float gin = bf2f(gis[(size_t)b * 3072 + 2048 + j]);
        float rr = 1.0f / (1.0f + expf(-(gir + bihr + acc[0][reg] + bhhr)));
        float zz = 1.0f / (1.0f + expf(-(giz + bihz + acc[1][reg] + bhhz)));
        float nn = tanhf(gin + bihn + rr * (acc[2][reg] + bhhn));
        float ho = h[(size_t)b * D_ + j];
        float hn = (1.0f - zz) * nn + zz * ho;
        h[(size_t)b * D_ + j] = hn;
        ushort hb = f2bf(hn);
        h_bf_out[(size_t)b * D_ + j] = hb;
        h_hist[((size_t)s * 64 + b) * D_ + j] = hb;
    }
}

// ---------------- proj chunk GEMM: ring[s][b][n] = h_hist[s][b] . projW[n] + projb[n] ----------------
// grid (CH, 16)
__global__ __launch_bounds__(256) void proj_gemm_kernel(const ushort* __restrict__ h_hist,
                                                        const ushort* __restrict__ projW_bf,
                                                        const float* __restrict__ projb,
                                                        ushort* __restrict__ ring) {
    int s = blockIdx.x;
    int n0 = blockIdx.y * 64;
    __shared__ ushort As[64][136];
    __shared__ ushort Bs[64][136];
    int tid = threadIdx.x;
    int w = tid >> 6, l = tid & 63, lr = l & 15, lk = l >> 4;
    f32x4 acc[4] = {};

    for (int kc = 0; kc < D_; kc += 128) {
        for (int u = tid; u < 1024; u += 256) {
            int r = u >> 4; int kp = (u & 15) * 8;
            *reinterpret_cast<uint4*>(&As[r][kp]) =
                *reinterpret_cast<const uint4*>(h_hist + ((size_t)s * 64 + r) * D_ + kc + kp);
        }
        for (int u = tid; u < 1024; u += 256) {
            int r = u >> 4; int kp = (u & 15) * 8;
            *reinterpret_cast<uint4*>(&Bs[r][kp]) =
                *reinterpret_cast<const uint4*>(projW_bf + (size_t)(n0 + r) * D_ + kc + kp);
        }
        __syncthreads();
        #pragma unroll
        for (int kk = 0; kk < 4; ++kk) {
            bf16x8 b = *reinterpret_cast<const bf16x8*>(&Bs[16 * w + lr][kk * 32 + lk * 8]);
            #pragma unroll
            for (int mi = 0; mi < 4; ++mi) {
                bf16x8 a = *reinterpret_cast<const bf16x8*>(&As[16 * mi + lr][kk * 32 + lk * 8]);
                acc[mi] = __builtin_amdgcn_mfma_f32_16x16x32_bf16(a, b, acc[mi], 0, 0, 0);
            }
        }
        __syncthreads();
    }
    int n = n0 + 16 * w + lr;
    float pb = projb[n];
    #pragma unroll
    for (int mi = 0; mi < 4; ++mi) {
        #pragma unroll
        for (int reg = 0; reg < 4; ++reg) {
            int b = 16 * mi + 4 * lk + reg;
            ring[((size_t)s * 64 + b) * D_ + n] = f2bf(acc[mi][reg] + pb);
        }
    }
}

// ---------------- CPC loss for one chunk (ring is bf16) ----------------
__global__ __launch_bounds__(256) void cpc_loss_kernel(const ushort* __restrict__ ring,
                                                       const float* __restrict__ Z,
                                                       double* __restrict__ cp_sum,
                                                       int t0) {
    int slot = blockIdx.x;
    int tp = t0 + slot;
    int k = blockIdx.y + 1;
    if (tp >= T_ - k) return;
    __shared__ float Hs[64][33];
    __shared__ float Zs[64][33];
    int tid = threadIdx.x;
    int tx = tid & 15, ty = tid >> 4;
    float acc[4][4] = {};
    const ushort* Hbase = ring + (size_t)slot * (B_ * D_);
    const float* Zbase = Z + (size_t)(tp + k) * D_;
    const size_t zstride = (size_t)T_ * D_;
    int r = tid >> 3, c = (tid & 7) << 2;

    for (int kc = 0; kc < D_; kc += 32) {
        #pragma unroll
        for (int p = 0; p < 2; ++p) {
            int rr2 = r + 32 * p;
            ushort4 hv = *reinterpret_cast<const ushort4*>(Hbase + (size_t)rr2 * D_ + kc + c);
            float4 zv = *reinterpret_cast<const float4*>(Zbase + (size_t)rr2 * zstride + kc + c);
            Hs[rr2][c] = bf2f(hv.x); Hs[rr2][c+1] = bf2f(hv.y);
            Hs[rr2][c+2] = bf2f(hv.z); Hs[rr2][c+3] = bf2f(hv.w);
            Zs[rr2][c] = zv.x; Zs[rr2][c+1] = zv.y; Zs[rr2][c+2] = zv.z; Zs[rr2][c+3] = zv.w;
        }
        __syncthreads();
        #pragma unroll
        for (int kk = 0; kk < 32; ++kk) {
            float av[4], bv[4];
            #pragma unroll
            for (int i = 0; i < 4; ++i) av[i] = Hs[ty + 16*i][kk];
            #pragma unroll
            for (int j = 0; j < 4; ++j) bv[j] = Zs[tx + 16*j][kk];
            #pragma unroll
            for (int i = 0; i < 4; ++i)
                #pragma unroll
                for (int j = 0; j < 4; ++j)
                    acc[i][j] = __fmaf_rn(av[i], bv[j], acc[i][j]);
        }
        __syncthreads();
    }

    double lsum = 0.0;
    #pragma unroll
    for (int i = 0; i < 4; ++i) {
        #pragma unroll
        for (int j = 0; j < 4; ++j) {
            int bb = ty + 16*i, cc2 = tx + 16*j;
            double v = (double)acc[i][j];
            double sg = 1.0 / (1.0 + exp(-v));
            lsum += (0.1 / 4096.0) * (-log(1.0 - sg + 1e-8));
            if (bb == cc2) lsum += (1.0 / 64.0) * (-log(sg + 1e-8));
        }
    }
    __shared__ double red[256];
    red[tid] = lsum; __syncthreads();
    for (int s2 = 128; s2 > 0; s2 >>= 1) {
        if (tid < s2) red[tid] += red[tid + s2];
        __syncthreads();
    }
    if (tid == 0) atomicAdd(cp_sum, red[0]);
}

// ---------------- VQ loss ----------------
__global__ __launch_bounds__(256) void vq_kernel(const float* __restrict__ Z,
                                                 const float* __restrict__ Q,
                                                 double* __restrict__ vq_sum) {
    size_t i0 = ((size_t)blockIdx.x * 256 + threadIdx.x) * 4;
    const size_t stride = (size_t)2048 * 256 * 4;
    double s = 0.0;
    for (size_t i = i0; i < (size_t)NQ_; i += stride) {
        float4 z = *reinterpret_cast<const float4*>(Z + i);
        float4 q = *reinterpret_cast<const float4*>(Q + i);
        double d0 = (double)z.x - (double)q.x;
        double d1 = (double)z.y - (double)q.y;
        double d2 = (double)z.z - (double)q.z;
        double d3 = (double)z.w - (double)q.w;
        s += d0*d0 + d1*d1 + d2*d2 + d3*d3;
    }
    __shared__ double red[256];
    int tid = threadIdx.x;
    red[tid] = s; __syncthreads();
    for (int k = 128; k > 0; k >>= 1) {
        if (tid < k) red[tid] += red[tid + k];
        __syncthreads();
    }
    if (tid == 0) atomicAdd(vq_sum, red[0]);
}

// ---------------- finalize scalars ----------------
__global__ void finalize_kernel(const double* __restrict__ accum,
                                float* __restrict__ scal) {
    double cp = accum[0] / 1527.0;
    double vq = accum[1] * 1.25 / (double)NQ_;
    scal[0] = (float)(cp + vq);
    scal[1] = (float)cp;
    scal[2] = (float)vq;
}

extern "C" void kernel_launch(void* const* d_in, const int* in_sizes, int n_in,
                              void* d_out, int out_size, void* d_ws, size_t ws_size,
                              hipStream_t stream) {
    const float* Z     = (const float*)d_in[0];
    const float* cb    = (const float*)d_in[1];
    const float* Wih   = (const float*)d_in[2];
    const float* Whh   = (const float*)d_in[3];
    const float* bih   = (const float*)d_in[4];
    const float* bhh   = (const float*)d_in[5];
    const float* projW = (const float*)d_in[6];
    const float* projb = (const float*)d_in[7];

    float* out       = (float*)d_out;
    float* quantized = out;
    float* idxout    = out + (size_t)NQ_;
    float* scal      = out + (size_t)NQ_ + NI_;

    // ws layout: fixed region + CH-scaled region
    char* p = (char*)d_ws;
    ushort* Whh_bf  = (ushort*)p;  p += 6291456;
    ushort* Wih_bf  = (ushort*)p;  p += 6291456;
    ushort* projW_bf= (ushort*)p;  p += 2097152;
    float*  h       = (float*)p;   p += 262144;
    ushort* h_bf0   = (ushort*)p;  p += 131072;
    ushort* h_bf1   = (ushort*)p;  p += 131072;
    float*  c2f     = (float*)p;   p += 4096;
    double* accum   = (double*)p;  p += 4096;
    size_t fixedsz = (size_t)(p - (char*)d_ws);

    static const int chs[7] = {64, 32, 16, 8, 4, 2, 1};
    int CH = 1;
    for (int i = 0; i < 7; ++i) {
        if (fixedsz + (size_t)chs[i] * 655360u <= ws_size) { CH = chs[i]; break; }
    }
    ushort* gi     = (ushort*)p;   p += (size_t)CH * 393216;
    ushort* h_hist = (ushort*)p;   p += (size_t)CH * 131072;
    ushort* ring   = (ushort*)p;

    hipMemsetAsync(h, 0, 262144, stream);
    hipMemsetAsync(h_bf0, 0, 131072, stream);
    hipMemsetAsync(h_bf1, 0, 131072, stream);
    hipMemsetAsync(accum, 0, 16, stream);

    conv_kernel<<<3072, 256, 0, stream>>>(Whh,   Whh_bf,   3145728);
    conv_kernel<<<3072, 256, 0, stream>>>(Wih,   Wih_bf,   3145728);
    conv_kernel<<<1024, 256, 0, stream>>>(projW, projW_bf, 1048576);

    c2_kernel<<<1, 256, 0, stream>>>(cb, c2f);
    quantize_kernel<<<4096, 256, 0, stream>>>(Z, cb, c2f, quantized, idxout);

    for (int c = 0; c < T_ / CH; ++c) {
        int t0 = c * CH;
        gi_gemm_kernel<<<dim3(CH, 48), 256, 0, stream>>>(quantized, Wih_bf, gi, t0);
        for (int s = 0; s < CH; ++s) {
            int t = t0 + s;
            const ushort* hin = (t & 1) ? h_bf1 : h_bf0;
            ushort*       hout = (t & 1) ? h_bf0 : h_bf1;
            fused_step_kernel<<<64, 256, 0, stream>>>(Whh_bf, gi, bih, bhh,
                                                      h, hin, hout, h_hist, s);
        }
        proj_gemm_kernel<<<dim3(CH, 16), 256, 0, stream>>>(h_hist, projW_bf, projb, ring);
        cpc_loss_kernel<<<dim3(CH, 3), 256, 0, stream>>>(ring, Z, &accum[0], t0);
    }

    vq_kernel<<<2048, 256, 0, stream>>>(Z, quantized, &accum[1]);
    finalize_kernel<<<1, 1, 0, stream>>>(accum, scal);
}